// Round 15
// baseline (96.613 us; speedup 1.0000x reference)
//
#include <hip/hip_runtime.h>

#define N 768
#define E 24576
#define NPAD_SLOTS (E + 3 * 768)      // 26880 max padded CSR slots
#define NGROUPS (NPAD_SLOTS / 4)      // 6720 K=32 groups

typedef __attribute__((ext_vector_type(8))) short bf16x8;
typedef __attribute__((ext_vector_type(4))) float f32x4;

// ---------------------------------------------------------------------------
// MFMA helpers — slot convention validated on HW (rounds 7-13):
// A/B lane (col, hi): slots j0-3 = k=hi*4+j, j4-7 = k=16+hi*4+j (lo 16b = even)
// C/D lane (col, hi): D[row = hi*4+r][col].
// ---------------------------------------------------------------------------
__device__ __forceinline__ unsigned pk2(float lo, float hi) {
  unsigned r;
  asm("v_cvt_pk_bf16_f32 %0, %1, %2" : "=v"(r) : "v"(lo), "v"(hi));
  return r;
}

union FragU {
  unsigned u[4];
  bf16x8 s;
};

__device__ __forceinline__ bf16x8 pack_frag(float4 a, float4 b) {
  FragU f;
  f.u[0] = pk2(a.x, a.y);
  f.u[1] = pk2(a.z, a.w);
  f.u[2] = pk2(b.x, b.y);
  f.u[3] = pk2(b.z, b.w);
  return f.s;
}

__device__ __forceinline__ bf16x8 relu_pack(f32x4 d1, f32x4 d2) {
  FragU f;
  f.u[0] = pk2(fmaxf(d1[0], 0.f), fmaxf(d1[1], 0.f));
  f.u[1] = pk2(fmaxf(d1[2], 0.f), fmaxf(d1[3], 0.f));
  f.u[2] = pk2(fmaxf(d2[0], 0.f), fmaxf(d2[1], 0.f));
  f.u[3] = pk2(fmaxf(d2[2], 0.f), fmaxf(d2[3], 0.f));
  return f.s;
}

__device__ __forceinline__ f32x4 ld4(const float* p) {
  float4 v = *(const float4*)p;
  f32x4 r;
  r[0] = v.x; r[1] = v.y; r[2] = v.z; r[3] = v.w;
  return r;
}

// ---------------------------------------------------------------------------
// prep0 = transpose (blocks 0..2303) + workspace init (blocks 2304..3983).
// ---------------------------------------------------------------------------
__global__ __launch_bounds__(256) void prep0(
    const float* __restrict__ mtr, uint4* __restrict__ mtrT,
    int4* __restrict__ winner4, uint4* __restrict__ Mfrag4,
    int* __restrict__ jlist, int* __restrict__ deg, int* __restrict__ curs,
    int* __restrict__ done_ctr) {
  __shared__ float lds[16][16 * 8 + 4];
  if (blockIdx.x < 2304) {
    const int r = threadIdx.x >> 4;
    const int c = threadIdx.x & 15;
    const size_t j0 = (size_t)(blockIdx.x % 48) * 16;
    const size_t i0 = (size_t)(blockIdx.x / 48) * 16;

    const float4* src = (const float4*)(mtr + ((i0 + r) * N + (j0 + c)) * 8);
    float4 a = src[0], b = src[1];
    *(float4*)&lds[r][c * 8 + 0] = a;
    *(float4*)&lds[r][c * 8 + 4] = b;
    __syncthreads();
    float4 ta = *(float4*)&lds[c][r * 8 + 0];
    float4 tb = *(float4*)&lds[c][r * 8 + 4];
    uint4 o;
    o.x = pk2(ta.x, ta.y); o.y = pk2(ta.z, ta.w);
    o.z = pk2(tb.x, tb.y); o.w = pk2(tb.z, tb.w);
    mtrT[(j0 + r) * N + (i0 + c)] = o;
  } else {
    const int t = (blockIdx.x - 2304) * 256 + threadIdx.x;  // < 430080 exact
    Mfrag4[t] = make_uint4(0, 0, 0, 0);  // NGROUPS*1024B / 16 = 430080
    if (t < 147456) winner4[t] = make_int4(-1, -1, -1, -1);
    if (t < NPAD_SLOTS) jlist[t] = 0;
    if (t < 1024) { deg[t] = 0; curs[t] = 0; }
    if (t == 0) *done_ctr = 0;
  }
}

// ---------------------------------------------------------------------------
// edge_prep + last-block fused scan (unchanged).
// ---------------------------------------------------------------------------
__global__ __launch_bounds__(256) void edge_prep_scan(
    const int* __restrict__ ei, int* __restrict__ winner,
    int* __restrict__ deg, int* __restrict__ offs,
    int* __restrict__ done_ctr) {
  const int e = blockIdx.x * 256 + threadIdx.x;  // grid 96*256 = E exact
  const int s = ei[e];
  const int d = ei[E + e];
  atomicMax(&winner[(size_t)s * N + d], e);
  atomicAdd(&deg[d], 1);

  __threadfence();
  __syncthreads();
  __shared__ int ticket;
  if (threadIdx.x == 0) ticket = atomicAdd(done_ctr, 1);
  __syncthreads();
  if (ticket == (E / 256) - 1 && threadIdx.x < 64) {
    const int lane = threadIdx.x;
    int v[12];
    int sum = 0;
#pragma unroll
    for (int z = 0; z < 12; ++z) {
      v[z] = (atomicAdd(&deg[lane * 12 + z], 0) + 3) & ~3;  // ceil4 pad
      sum += v[z];
    }
    int inc = sum;
#pragma unroll
    for (int dd = 1; dd < 64; dd <<= 1) {
      int t = __shfl_up(inc, dd, 64);
      if (lane >= dd) inc += t;
    }
    int run = inc - sum;
#pragma unroll
    for (int z = 0; z < 12; ++z) {
      run += v[z];
      offs[lane * 12 + z + 1] = run;
    }
    if (lane == 0) offs[0] = 0;
  }
}

// ---------------------------------------------------------------------------
// Edge MLP via MFMA with fused CSR scatter and fragment repack (unchanged).
// ---------------------------------------------------------------------------
__global__ __launch_bounds__(256) void edge_mlp_mfma(
    const float* __restrict__ feat, const int* __restrict__ ei,
    const float* __restrict__ ea, const int* __restrict__ winner,
    const int* __restrict__ offs, int* __restrict__ curs,
    int* __restrict__ jlist,
    const float* __restrict__ w0, const float* __restrict__ b0,
    const float* __restrict__ w1, const float* __restrict__ b1,
    const float* __restrict__ w2, const float* __restrict__ b2,
    const float* __restrict__ w3, const float* __restrict__ b3,
    short* __restrict__ Mfrag) {
  __shared__ float Ld[4][16 * 65];
  const int wv = threadIdx.x >> 6;
  const int lane = threadIdx.x & 63;
  const int col = lane & 15;
  const int hi = lane >> 4;
  const int e = (blockIdx.x * 4 + wv) * 16 + col;

  const float4 z4 = make_float4(0.f, 0.f, 0.f, 0.f);

  const int s = ei[e];
  const int d = ei[E + e];
  int pos = -1;
  if (hi == 0) {
    if (winner[(size_t)s * N + d] == e) {
      pos = offs[d] + atomicAdd(&curs[d], 1);
      jlist[pos] = s;
    }
  }
  pos = __shfl(pos, col, 64);

  const float* pa = (hi == 0) ? (ea + (size_t)e * 4)
                  : (hi == 1) ? (feat + (size_t)s * 8)
                  : (hi == 2) ? (feat + (size_t)s * 8 + 4)
                              : (feat + (size_t)d * 8);
  float4 va = *(const float4*)pa;
  float4 vb = (hi == 0) ? *(const float4*)(feat + (size_t)d * 8 + 4) : z4;
  bf16x8 bfr = pack_frag(va, vb);

  bf16x8 a0lo, a0hi, a1lo, a1hi, a2lo, a2hi, a3f[4];
  {
    const float* p = w0 + col * 20;
    float4 xa = *(const float4*)(p + hi * 4);
    float4 xb = (hi == 0) ? *(const float4*)(p + 16) : z4;
    a0lo = pack_frag(xa, xb);
    const float* q = w0 + (col + 16) * 20;
    float4 ya = *(const float4*)(q + hi * 4);
    float4 yb = (hi == 0) ? *(const float4*)(q + 16) : z4;
    a0hi = pack_frag(ya, yb);
  }
  a1lo = pack_frag(*(const float4*)(w1 + col * 32 + hi * 4),
                   *(const float4*)(w1 + col * 32 + 16 + hi * 4));
  a1hi = pack_frag(*(const float4*)(w1 + (col + 16) * 32 + hi * 4),
                   *(const float4*)(w1 + (col + 16) * 32 + 16 + hi * 4));
  a2lo = pack_frag(*(const float4*)(w2 + col * 32 + hi * 4),
                   *(const float4*)(w2 + col * 32 + 16 + hi * 4));
  a2hi = pack_frag(*(const float4*)(w2 + (col + 16) * 32 + hi * 4),
                   *(const float4*)(w2 + (col + 16) * 32 + 16 + hi * 4));
#pragma unroll
  for (int q = 0; q < 4; ++q) {
    const float* p = w3 + (size_t)(q * 16 + col) * 32;
    a3f[q] = pack_frag(*(const float4*)(p + hi * 4),
                       *(const float4*)(p + 16 + hi * 4));
  }

  f32x4 d1 = ld4(b0 + hi * 4), d2 = ld4(b0 + 16 + hi * 4);
  d1 = __builtin_amdgcn_mfma_f32_16x16x32_bf16(a0lo, bfr, d1, 0, 0, 0);
  d2 = __builtin_amdgcn_mfma_f32_16x16x32_bf16(a0hi, bfr, d2, 0, 0, 0);
  bfr = relu_pack(d1, d2);

  d1 = ld4(b1 + hi * 4); d2 = ld4(b1 + 16 + hi * 4);
  d1 = __builtin_amdgcn_mfma_f32_16x16x32_bf16(a1lo, bfr, d1, 0, 0, 0);
  d2 = __builtin_amdgcn_mfma_f32_16x16x32_bf16(a1hi, bfr, d2, 0, 0, 0);
  bfr = relu_pack(d1, d2);

  d1 = ld4(b2 + hi * 4); d2 = ld4(b2 + 16 + hi * 4);
  d1 = __builtin_amdgcn_mfma_f32_16x16x32_bf16(a2lo, bfr, d1, 0, 0, 0);
  d2 = __builtin_amdgcn_mfma_f32_16x16x32_bf16(a2hi, bfr, d2, 0, 0, 0);
  bfr = relu_pack(d1, d2);

  // ---- layer 3: D rows o = q*16 + hi*4 + r; park M[o = c*8+t] in LDS ----
#pragma unroll
  for (int q = 0; q < 4; ++q) {
    f32x4 d3 = ld4(b3 + q * 16 + hi * 4);
    d3 = __builtin_amdgcn_mfma_f32_16x16x32_bf16(a3f[q], bfr, d3, 0, 0, 0);
#pragma unroll
    for (int r = 0; r < 4; ++r)
      Ld[wv][col * 65 + q * 16 + hi * 4 + r] = d3[r];
  }
  __syncthreads();

  // ---- direct fragment write: lane hi handles hl = hi>>1, t = (hi&1)*4.. ----
  if (pos >= 0) {
    const int gid = pos >> 2;
    const int sg = pos & 3;
    short* base = Mfrag + (size_t)gid * 512 + (sg & 1) * 256 + (sg >> 1) * 4;
    const int hl = hi >> 1;
    const int t0 = (hi & 1) * 4;
    const float* m = &Ld[wv][col * 65];
#pragma unroll
    for (int cc = 0; cc < 4; ++cc) {
      const int t = t0 + cc;
      unsigned u0 = pk2(m[(hl * 4 + 0) * 8 + t], m[(hl * 4 + 1) * 8 + t]);
      unsigned u1 = pk2(m[(hl * 4 + 2) * 8 + t], m[(hl * 4 + 3) * 8 + t]);
      *(uint2*)(base + hl * 128 + t * 8) = make_uint2(u0, u1);
    }
  }
}

// ---------------------------------------------------------------------------
// Walk contraction v7 — MFMA, WT output in bf16 (unchanged from round 13).
// ---------------------------------------------------------------------------
__global__ __launch_bounds__(256) void contract7(
    const short* __restrict__ mtrT, const short* __restrict__ Mfrag,
    const int* __restrict__ jlist, const int* __restrict__ offs,
    const int* __restrict__ wcnt, short* __restrict__ WTb) {
  __shared__ float sD[4][4][16][9];

  const int bid = blockIdx.x;
  const int g = (bid & 7) * 288 + (bid >> 3);  // XCD-chunked: 2304 = 8*288
  const int ig = g / 768;                      // i-slab 0..2 (256 i each)
  const int k = g % 768;
  const int w = threadIdx.x >> 6;
  const int lane = threadIdx.x & 63;
  const int col = lane & 15;
  const int hi = lane >> 4;
  const int ibase = ig * 256 + w * 64;

  const int base = offs[k];   // % 4 == 0 by construction
  const int cnt = wcnt[k];
  const int ngr = (cnt + 3) >> 2;

  f32x4 acc0 = {0.f, 0.f, 0.f, 0.f}, acc1 = {0.f, 0.f, 0.f, 0.f};
  f32x4 acc2 = {0.f, 0.f, 0.f, 0.f}, acc3 = {0.f, 0.f, 0.f, 0.f};

  const size_t lane_off = ((size_t)(ibase + col)) * 8 + (hi & 1) * 4;

#pragma unroll 2
  for (int gg = 0; gg < ngr; ++gg) {
    const int4 js = *(const int4*)(jlist + base + gg * 4);  // uniform
    const int ja = (hi & 2) ? js.y : js.x;
    const int jb = (hi & 2) ? js.w : js.z;

    bf16x8 bfr = *(const bf16x8*)(
        Mfrag + ((size_t)(base >> 2) + gg) * 512 + lane * 8);

    const short* pa = mtrT + (size_t)ja * (N * 8) + lane_off;
    const short* pb = mtrT + (size_t)jb * (N * 8) + lane_off;

#define TILE(ACC, T)                                                     \
  do {                                                                   \
    uint2 ua = *(const uint2*)(pa + (T) * (16 * 8));                     \
    uint2 ub = *(const uint2*)(pb + (T) * (16 * 8));                     \
    FragU af;                                                            \
    af.u[0] = ua.x; af.u[1] = ua.y; af.u[2] = ub.x; af.u[3] = ub.y;      \
    ACC = __builtin_amdgcn_mfma_f32_16x16x32_bf16(af.s, bfr, ACC, 0, 0, 0); \
  } while (0)

    TILE(acc0, 0);
    TILE(acc1, 1);
    TILE(acc2, 2);
    TILE(acc3, 3);
#undef TILE
  }

  // ---- epilogue: D lane (col=t, hi) holds D[i_loc=hi*4+r][t=col] ----
  if (col < 8) {
#pragma unroll
    for (int r = 0; r < 4; ++r) {
      sD[w][0][hi * 4 + r][col] = acc0[r] * 0.125f;
      sD[w][1][hi * 4 + r][col] = acc1[r] * 0.125f;
      sD[w][2][hi * 4 + r][col] = acc2[r] * 0.125f;
      sD[w][3][hi * 4 + r][col] = acc3[r] * 0.125f;
    }
  }
  __syncthreads();
  if (lane < 16) {
#pragma unroll
    for (int t = 0; t < 4; ++t) {
      const float* row = &sD[w][t][lane][0];
      uint4 o;
      o.x = pk2(row[0], row[1]); o.y = pk2(row[2], row[3]);
      o.z = pk2(row[4], row[5]); o.w = pk2(row[6], row[7]);
      *(uint4*)(WTb + ((size_t)k * N + ibase + t * 16 + lane) * 8) = o;
    }
  }
}

// ---------------------------------------------------------------------------
// Output MLP via MFMA v2: grid 2304 = 8 XCD-chunks x (96 i x 3 kc).
// Each XCD owns 96 contiguous i's (gathered WTb[krow][i] lines fully
// consumed within one XCD L2); each wave does 4 k-groups (more TLP:
// 9 blocks/CU requested vs 3 before).
// ---------------------------------------------------------------------------
__global__ __launch_bounds__(256, 2) void out_mlp_mfma(
    const float* __restrict__ mtr, const short* __restrict__ WTb,
    const float* __restrict__ feat,
    const float* __restrict__ w0, const float* __restrict__ b0,
    const float* __restrict__ w1, const float* __restrict__ b1,
    const float* __restrict__ w2, const float* __restrict__ b2,
    const float* __restrict__ w3, const float* __restrict__ b3,
    float* __restrict__ out) {
  const int b = blockIdx.x;                // 2304 = 8 * 288
  const int xcd = b & 7;
  const int loc = b >> 3;                  // 0..287
  const int i = xcd * 96 + (loc % 96);
  const int kc = loc / 96;                 // 0..2
  const int w = threadIdx.x >> 6;
  const int col = threadIdx.x & 15;
  const int hi = (threadIdx.x >> 4) & 3;

  bf16x8 a0lo, a0hi, a1lo, a1hi, a2lo, a2hi, a3;
  {
    const float* p = w0 + col * 33;
    float4 xa = make_float4(p[hi * 4], p[hi * 4 + 1], p[hi * 4 + 2], p[hi * 4 + 3]);
    float4 xb = make_float4(p[16 + hi * 4], p[16 + hi * 4 + 1],
                            p[16 + hi * 4 + 2], p[16 + hi * 4 + 3]);
    a0lo = pack_frag(xa, xb);
    const float* q = w0 + (col + 16) * 33;
    float4 ya = make_float4(q[hi * 4], q[hi * 4 + 1], q[hi * 4 + 2], q[hi * 4 + 3]);
    float4 yb = make_float4(q[16 + hi * 4], q[16 + hi * 4 + 1],
                            q[16 + hi * 4 + 2], q[16 + hi * 4 + 3]);
    a0hi = pack_frag(ya, yb);
  }
  a1lo = pack_frag(*(const float4*)(w1 + col * 32 + hi * 4),
                   *(const float4*)(w1 + col * 32 + 16 + hi * 4));
  a1hi = pack_frag(*(const float4*)(w1 + (col + 16) * 32 + hi * 4),
                   *(const float4*)(w1 + (col + 16) * 32 + 16 + hi * 4));
  a2lo = pack_frag(*(const float4*)(w2 + col * 32 + hi * 4),
                   *(const float4*)(w2 + col * 32 + 16 + hi * 4));
  a2hi = pack_frag(*(const float4*)(w2 + (col + 16) * 32 + hi * 4),
                   *(const float4*)(w2 + (col + 16) * 32 + 16 + hi * 4));
  if (col < 8) {
    a3 = pack_frag(*(const float4*)(w3 + col * 32 + hi * 4),
                   *(const float4*)(w3 + col * 32 + 16 + hi * 4));
  } else {
    FragU z; z.u[0] = z.u[1] = z.u[2] = z.u[3] = 0; a3 = z.s;
  }

  const f32x4 c1a = ld4(b0 + hi * 4), c1b = ld4(b0 + 16 + hi * 4);
  const f32x4 c2a = ld4(b1 + hi * 4), c2b = ld4(b1 + 16 + hi * 4);
  const f32x4 c3a = ld4(b2 + hi * 4), c3b = ld4(b2 + 16 + hi * 4);
  f32x4 c4;
  if (hi < 2) c4 = ld4(b3 + hi * 4);
  else { c4[0] = c4[1] = c4[2] = c4[3] = 0.f; }

  float dg1[4], dg2[4];
#pragma unroll
  for (int r = 0; r < 4; ++r) {
    dg1[r] = w0[(hi * 4 + r) * 33 + 32];
    dg2[r] = w0[(16 + hi * 4 + r) * 33 + 32];
  }

#pragma unroll 1
  for (int g = 0; g < 4; ++g) {
    const int krow = kc * 256 + w * 64 + g * 16 + col;

    FragU bf;
    const short* pW = (hi < 2)
        ? (WTb + ((size_t)krow * N + i) * 8 + (hi & 1) * 4)
        : (WTb + ((size_t)i * N + krow) * 8 + (hi & 1) * 4);
    uint2 wv2 = *(const uint2*)pW;
    const float* pF = (hi < 2) ? (feat + (size_t)krow * 8 + (hi & 1) * 4)
                               : (feat + (size_t)i * 8 + (hi & 1) * 4);
    float4 fv = *(const float4*)pF;
    bf.u[0] = wv2.x; bf.u[1] = wv2.y;
    bf.u[2] = pk2(fv.x, fv.y); bf.u[3] = pk2(fv.z, fv.w);
    bf16x8 bfr = bf.s;

    f32x4 d1 = c1a, d2 = c1b;
    d1 = __builtin_amdgcn_mfma_f32_16x16x32_bf16(a0lo, bfr, d1, 0, 0, 0);
    d2 = __builtin_amdgcn_mfma_f32_16x16x32_bf16(a0hi, bfr, d2, 0, 0, 0);
    const float eye = (krow == i) ? 1.f : 0.f;
#pragma unroll
    for (int r = 0; r < 4; ++r) {
      d1[r] = fmaf(eye, dg1[r], d1[r]);
      d2[r] = fmaf(eye, dg2[r], d2[r]);
    }
    bfr = relu_pack(d1, d2);

    d1 = c2a; d2 = c2b;
    d1 = __builtin_amdgcn_mfma_f32_16x16x32_bf16(a1lo, bfr, d1, 0, 0, 0);
    d2 = __builtin_amdgcn_mfma_f32_16x16x32_bf16(a1hi, bfr, d2, 0, 0, 0);
    bfr = relu_pack(d1, d2);

    d1 = c3a; d2 = c3b;
    d1 = __builtin_amdgcn_mfma_f32_16x16x32_bf16(a2lo, bfr, d1, 0, 0, 0);
    d2 = __builtin_amdgcn_mfma_f32_16x16x32_bf16(a2hi, bfr, d2, 0, 0, 0);
    bfr = relu_pack(d1, d2);

    f32x4 d3 = c4;
    d3 = __builtin_amdgcn_mfma_f32_16x16x32_bf16(a3, bfr, d3, 0, 0, 0);

    if (hi < 2) {
      const size_t idx = ((size_t)i * N + krow) * 8 + hi * 4;
      float4 m = *(const float4*)(mtr + idx);
      *(float4*)(out + idx) =
          make_float4(m.x + d3[0], m.y + d3[1], m.z + d3[2], m.w + d3[3]);
    }
  }
}

// ---------------------------------------------------------------------------
extern "C" void kernel_launch(void* const* d_in, const int* in_sizes, int n_in,
                              void* d_out, int out_size, void* d_ws,
                              size_t ws_size, hipStream_t stream) {
  const float* mtr  = (const float*)d_in[0];
  const float* feat = (const float*)d_in[1];
  const int*   ei   = (const int*)d_in[2];
  const float* ea   = (const float*)d_in[3];
  const float* ew0 = (const float*)d_in[4];
  const float* eb0 = (const float*)d_in[5];
  const float* ew1 = (const float*)d_in[6];
  const float* eb1 = (const float*)d_in[7];
  const float* ew2 = (const float*)d_in[8];
  const float* eb2 = (const float*)d_in[9];
  const float* ew3 = (const float*)d_in[10];
  const float* eb3 = (const float*)d_in[11];
  const float* ow0 = (const float*)d_in[12];
  const float* ob0 = (const float*)d_in[13];
  const float* ow1 = (const float*)d_in[14];
  const float* ob1 = (const float*)d_in[15];
  const float* ow2 = (const float*)d_in[16];
  const float* ob2 = (const float*)d_in[17];
  const float* ow3 = (const float*)d_in[18];
  const float* ob3 = (const float*)d_in[19];
  float* out = (float*)d_out;

  char* ws = (char*)d_ws;
  short* Mfrag = (short*)ws; ws += (size_t)NGROUPS * 512 * 2;     // 6.88 MB
  short* mtrT  = (short*)ws; ws += (size_t)N * N * 8 * 2;         // 9.44 MB
  short* WTb   = (short*)ws; ws += (size_t)N * N * 8 * 2;         // 9.44 MB
  int* winner  = (int*)ws;   ws += (size_t)N * N * 4;             // 2.36 MB
  int* deg     = (int*)ws;   ws += 1024 * 4;
  int* offs    = (int*)ws;   ws += 1024 * 4;
  int* curs    = (int*)ws;   ws += 1024 * 4;
  int* done_ctr = (int*)ws;  ws += 256 * 4;
  int* jlist   = (int*)ws;   ws += (size_t)NPAD_SLOTS * 4;        // 108 KB

  prep0<<<2304 + 1680, 256, 0, stream>>>(mtr, (uint4*)mtrT, (int4*)winner,
                                         (uint4*)Mfrag, jlist, deg, curs,
                                         done_ctr);
  edge_prep_scan<<<E / 256, 256, 0, stream>>>(ei, winner, deg, offs, done_ctr);
  edge_mlp_mfma<<<E / 64, 256, 0, stream>>>(feat, ei, ea, winner, offs, curs,
                                            jlist, ew0, eb0, ew1, eb1, ew2,
                                            eb2, ew3, eb3, Mfrag);
  contract7<<<2304, 256, 0, stream>>>(mtrT, Mfrag, jlist, offs, curs, WTb);
  out_mlp_mfma<<<2304, 256, 0, stream>>>(mtr, WTb, feat, ow0, ob0, ow1, ob1,
                                         ow2, ob2, ow3, ob3, out);
}

// Round 16
// 88.350 us; speedup vs baseline: 1.0935x; 1.0935x over previous
//
#include <hip/hip_runtime.h>

#define N 768
#define E 24576
#define NPAD_SLOTS (E + 3 * 768)      // 26880 max padded CSR slots
#define NGROUPS (NPAD_SLOTS / 4)      // 6720 K=32 groups

typedef __attribute__((ext_vector_type(8))) short bf16x8;
typedef __attribute__((ext_vector_type(4))) float f32x4;

// ---------------------------------------------------------------------------
// MFMA helpers — slot convention validated on HW (rounds 7-13):
// A/B lane (col, hi): slots j0-3 = k=hi*4+j, j4-7 = k=16+hi*4+j (lo 16b = even)
// C/D lane (col, hi): D[row = hi*4+r][col].
// ---------------------------------------------------------------------------
__device__ __forceinline__ unsigned pk2(float lo, float hi) {
  unsigned r;
  asm("v_cvt_pk_bf16_f32 %0, %1, %2" : "=v"(r) : "v"(lo), "v"(hi));
  return r;
}

union FragU {
  unsigned u[4];
  bf16x8 s;
};

__device__ __forceinline__ bf16x8 pack_frag(float4 a, float4 b) {
  FragU f;
  f.u[0] = pk2(a.x, a.y);
  f.u[1] = pk2(a.z, a.w);
  f.u[2] = pk2(b.x, b.y);
  f.u[3] = pk2(b.z, b.w);
  return f.s;
}

__device__ __forceinline__ bf16x8 relu_pack(f32x4 d1, f32x4 d2) {
  FragU f;
  f.u[0] = pk2(fmaxf(d1[0], 0.f), fmaxf(d1[1], 0.f));
  f.u[1] = pk2(fmaxf(d1[2], 0.f), fmaxf(d1[3], 0.f));
  f.u[2] = pk2(fmaxf(d2[0], 0.f), fmaxf(d2[1], 0.f));
  f.u[3] = pk2(fmaxf(d2[2], 0.f), fmaxf(d2[3], 0.f));
  return f.s;
}

__device__ __forceinline__ f32x4 ld4(const float* p) {
  float4 v = *(const float4*)p;
  f32x4 r;
  r[0] = v.x; r[1] = v.y; r[2] = v.z; r[3] = v.w;
  return r;
}

// ---------------------------------------------------------------------------
// prep0 = transpose (blocks 0..2303) + workspace init (blocks 2304..3983).
// ---------------------------------------------------------------------------
__global__ __launch_bounds__(256) void prep0(
    const float* __restrict__ mtr, uint4* __restrict__ mtrT,
    int4* __restrict__ winner4, uint4* __restrict__ Mfrag4,
    int* __restrict__ jlist, int* __restrict__ deg, int* __restrict__ curs,
    int* __restrict__ done_ctr) {
  __shared__ float lds[16][16 * 8 + 4];
  if (blockIdx.x < 2304) {
    const int r = threadIdx.x >> 4;
    const int c = threadIdx.x & 15;
    const size_t j0 = (size_t)(blockIdx.x % 48) * 16;
    const size_t i0 = (size_t)(blockIdx.x / 48) * 16;

    const float4* src = (const float4*)(mtr + ((i0 + r) * N + (j0 + c)) * 8);
    float4 a = src[0], b = src[1];
    *(float4*)&lds[r][c * 8 + 0] = a;
    *(float4*)&lds[r][c * 8 + 4] = b;
    __syncthreads();
    float4 ta = *(float4*)&lds[c][r * 8 + 0];
    float4 tb = *(float4*)&lds[c][r * 8 + 4];
    uint4 o;
    o.x = pk2(ta.x, ta.y); o.y = pk2(ta.z, ta.w);
    o.z = pk2(tb.x, tb.y); o.w = pk2(tb.z, tb.w);
    mtrT[(j0 + r) * N + (i0 + c)] = o;
  } else {
    const int t = (blockIdx.x - 2304) * 256 + threadIdx.x;  // < 430080 exact
    Mfrag4[t] = make_uint4(0, 0, 0, 0);  // NGROUPS*1024B / 16 = 430080
    if (t < 147456) winner4[t] = make_int4(-1, -1, -1, -1);
    if (t < NPAD_SLOTS) jlist[t] = 0;
    if (t < 1024) { deg[t] = 0; curs[t] = 0; }
    if (t == 0) *done_ctr = 0;
  }
}

// ---------------------------------------------------------------------------
// edge_prep + last-block fused scan (unchanged).
// ---------------------------------------------------------------------------
__global__ __launch_bounds__(256) void edge_prep_scan(
    const int* __restrict__ ei, int* __restrict__ winner,
    int* __restrict__ deg, int* __restrict__ offs,
    int* __restrict__ done_ctr) {
  const int e = blockIdx.x * 256 + threadIdx.x;  // grid 96*256 = E exact
  const int s = ei[e];
  const int d = ei[E + e];
  atomicMax(&winner[(size_t)s * N + d], e);
  atomicAdd(&deg[d], 1);

  __threadfence();
  __syncthreads();
  __shared__ int ticket;
  if (threadIdx.x == 0) ticket = atomicAdd(done_ctr, 1);
  __syncthreads();
  if (ticket == (E / 256) - 1 && threadIdx.x < 64) {
    const int lane = threadIdx.x;
    int v[12];
    int sum = 0;
#pragma unroll
    for (int z = 0; z < 12; ++z) {
      v[z] = (atomicAdd(&deg[lane * 12 + z], 0) + 3) & ~3;  // ceil4 pad
      sum += v[z];
    }
    int inc = sum;
#pragma unroll
    for (int dd = 1; dd < 64; dd <<= 1) {
      int t = __shfl_up(inc, dd, 64);
      if (lane >= dd) inc += t;
    }
    int run = inc - sum;
#pragma unroll
    for (int z = 0; z < 12; ++z) {
      run += v[z];
      offs[lane * 12 + z + 1] = run;
    }
    if (lane == 0) offs[0] = 0;
  }
}

// ---------------------------------------------------------------------------
// Edge MLP via MFMA with fused CSR scatter and fragment repack (unchanged).
// ---------------------------------------------------------------------------
__global__ __launch_bounds__(256) void edge_mlp_mfma(
    const float* __restrict__ feat, const int* __restrict__ ei,
    const float* __restrict__ ea, const int* __restrict__ winner,
    const int* __restrict__ offs, int* __restrict__ curs,
    int* __restrict__ jlist,
    const float* __restrict__ w0, const float* __restrict__ b0,
    const float* __restrict__ w1, const float* __restrict__ b1,
    const float* __restrict__ w2, const float* __restrict__ b2,
    const float* __restrict__ w3, const float* __restrict__ b3,
    short* __restrict__ Mfrag) {
  __shared__ float Ld[4][16 * 65];
  const int wv = threadIdx.x >> 6;
  const int lane = threadIdx.x & 63;
  const int col = lane & 15;
  const int hi = lane >> 4;
  const int e = (blockIdx.x * 4 + wv) * 16 + col;

  const float4 z4 = make_float4(0.f, 0.f, 0.f, 0.f);

  const int s = ei[e];
  const int d = ei[E + e];
  int pos = -1;
  if (hi == 0) {
    if (winner[(size_t)s * N + d] == e) {
      pos = offs[d] + atomicAdd(&curs[d], 1);
      jlist[pos] = s;
    }
  }
  pos = __shfl(pos, col, 64);

  const float* pa = (hi == 0) ? (ea + (size_t)e * 4)
                  : (hi == 1) ? (feat + (size_t)s * 8)
                  : (hi == 2) ? (feat + (size_t)s * 8 + 4)
                              : (feat + (size_t)d * 8);
  float4 va = *(const float4*)pa;
  float4 vb = (hi == 0) ? *(const float4*)(feat + (size_t)d * 8 + 4) : z4;
  bf16x8 bfr = pack_frag(va, vb);

  bf16x8 a0lo, a0hi, a1lo, a1hi, a2lo, a2hi, a3f[4];
  {
    const float* p = w0 + col * 20;
    float4 xa = *(const float4*)(p + hi * 4);
    float4 xb = (hi == 0) ? *(const float4*)(p + 16) : z4;
    a0lo = pack_frag(xa, xb);
    const float* q = w0 + (col + 16) * 20;
    float4 ya = *(const float4*)(q + hi * 4);
    float4 yb = (hi == 0) ? *(const float4*)(q + 16) : z4;
    a0hi = pack_frag(ya, yb);
  }
  a1lo = pack_frag(*(const float4*)(w1 + col * 32 + hi * 4),
                   *(const float4*)(w1 + col * 32 + 16 + hi * 4));
  a1hi = pack_frag(*(const float4*)(w1 + (col + 16) * 32 + hi * 4),
                   *(const float4*)(w1 + (col + 16) * 32 + 16 + hi * 4));
  a2lo = pack_frag(*(const float4*)(w2 + col * 32 + hi * 4),
                   *(const float4*)(w2 + col * 32 + 16 + hi * 4));
  a2hi = pack_frag(*(const float4*)(w2 + (col + 16) * 32 + hi * 4),
                   *(const float4*)(w2 + (col + 16) * 32 + 16 + hi * 4));
#pragma unroll
  for (int q = 0; q < 4; ++q) {
    const float* p = w3 + (size_t)(q * 16 + col) * 32;
    a3f[q] = pack_frag(*(const float4*)(p + hi * 4),
                       *(const float4*)(p + 16 + hi * 4));
  }

  f32x4 d1 = ld4(b0 + hi * 4), d2 = ld4(b0 + 16 + hi * 4);
  d1 = __builtin_amdgcn_mfma_f32_16x16x32_bf16(a0lo, bfr, d1, 0, 0, 0);
  d2 = __builtin_amdgcn_mfma_f32_16x16x32_bf16(a0hi, bfr, d2, 0, 0, 0);
  bfr = relu_pack(d1, d2);

  d1 = ld4(b1 + hi * 4); d2 = ld4(b1 + 16 + hi * 4);
  d1 = __builtin_amdgcn_mfma_f32_16x16x32_bf16(a1lo, bfr, d1, 0, 0, 0);
  d2 = __builtin_amdgcn_mfma_f32_16x16x32_bf16(a1hi, bfr, d2, 0, 0, 0);
  bfr = relu_pack(d1, d2);

  d1 = ld4(b2 + hi * 4); d2 = ld4(b2 + 16 + hi * 4);
  d1 = __builtin_amdgcn_mfma_f32_16x16x32_bf16(a2lo, bfr, d1, 0, 0, 0);
  d2 = __builtin_amdgcn_mfma_f32_16x16x32_bf16(a2hi, bfr, d2, 0, 0, 0);
  bfr = relu_pack(d1, d2);

  // ---- layer 3: D rows o = q*16 + hi*4 + r; park M[o = c*8+t] in LDS ----
#pragma unroll
  for (int q = 0; q < 4; ++q) {
    f32x4 d3 = ld4(b3 + q * 16 + hi * 4);
    d3 = __builtin_amdgcn_mfma_f32_16x16x32_bf16(a3f[q], bfr, d3, 0, 0, 0);
#pragma unroll
    for (int r = 0; r < 4; ++r)
      Ld[wv][col * 65 + q * 16 + hi * 4 + r] = d3[r];
  }
  __syncthreads();

  // ---- direct fragment write: lane hi handles hl = hi>>1, t = (hi&1)*4.. ----
  if (pos >= 0) {
    const int gid = pos >> 2;
    const int sg = pos & 3;
    short* base = Mfrag + (size_t)gid * 512 + (sg & 1) * 256 + (sg >> 1) * 4;
    const int hl = hi >> 1;
    const int t0 = (hi & 1) * 4;
    const float* m = &Ld[wv][col * 65];
#pragma unroll
    for (int cc = 0; cc < 4; ++cc) {
      const int t = t0 + cc;
      unsigned u0 = pk2(m[(hl * 4 + 0) * 8 + t], m[(hl * 4 + 1) * 8 + t]);
      unsigned u1 = pk2(m[(hl * 4 + 2) * 8 + t], m[(hl * 4 + 3) * 8 + t]);
      *(uint2*)(base + hl * 128 + t * 8) = make_uint2(u0, u1);
    }
  }
}

// ---------------------------------------------------------------------------
// Walk contraction v7 — MFMA, WT output in bf16 (unchanged from round 13).
// ---------------------------------------------------------------------------
__global__ __launch_bounds__(256) void contract7(
    const short* __restrict__ mtrT, const short* __restrict__ Mfrag,
    const int* __restrict__ jlist, const int* __restrict__ offs,
    const int* __restrict__ wcnt, short* __restrict__ WTb) {
  __shared__ float sD[4][4][16][9];

  const int bid = blockIdx.x;
  const int g = (bid & 7) * 288 + (bid >> 3);  // XCD-chunked: 2304 = 8*288
  const int ig = g / 768;                      // i-slab 0..2 (256 i each)
  const int k = g % 768;
  const int w = threadIdx.x >> 6;
  const int lane = threadIdx.x & 63;
  const int col = lane & 15;
  const int hi = lane >> 4;
  const int ibase = ig * 256 + w * 64;

  const int base = offs[k];   // % 4 == 0 by construction
  const int cnt = wcnt[k];
  const int ngr = (cnt + 3) >> 2;

  f32x4 acc0 = {0.f, 0.f, 0.f, 0.f}, acc1 = {0.f, 0.f, 0.f, 0.f};
  f32x4 acc2 = {0.f, 0.f, 0.f, 0.f}, acc3 = {0.f, 0.f, 0.f, 0.f};

  const size_t lane_off = ((size_t)(ibase + col)) * 8 + (hi & 1) * 4;

#pragma unroll 2
  for (int gg = 0; gg < ngr; ++gg) {
    const int4 js = *(const int4*)(jlist + base + gg * 4);  // uniform
    const int ja = (hi & 2) ? js.y : js.x;
    const int jb = (hi & 2) ? js.w : js.z;

    bf16x8 bfr = *(const bf16x8*)(
        Mfrag + ((size_t)(base >> 2) + gg) * 512 + lane * 8);

    const short* pa = mtrT + (size_t)ja * (N * 8) + lane_off;
    const short* pb = mtrT + (size_t)jb * (N * 8) + lane_off;

#define TILE(ACC, T)                                                     \
  do {                                                                   \
    uint2 ua = *(const uint2*)(pa + (T) * (16 * 8));                     \
    uint2 ub = *(const uint2*)(pb + (T) * (16 * 8));                     \
    FragU af;                                                            \
    af.u[0] = ua.x; af.u[1] = ua.y; af.u[2] = ub.x; af.u[3] = ub.y;      \
    ACC = __builtin_amdgcn_mfma_f32_16x16x32_bf16(af.s, bfr, ACC, 0, 0, 0); \
  } while (0)

    TILE(acc0, 0);
    TILE(acc1, 1);
    TILE(acc2, 2);
    TILE(acc3, 3);
#undef TILE
  }

  // ---- epilogue: D lane (col=t, hi) holds D[i_loc=hi*4+r][t=col] ----
  if (col < 8) {
#pragma unroll
    for (int r = 0; r < 4; ++r) {
      sD[w][0][hi * 4 + r][col] = acc0[r] * 0.125f;
      sD[w][1][hi * 4 + r][col] = acc1[r] * 0.125f;
      sD[w][2][hi * 4 + r][col] = acc2[r] * 0.125f;
      sD[w][3][hi * 4 + r][col] = acc3[r] * 0.125f;
    }
  }
  __syncthreads();
  if (lane < 16) {
#pragma unroll
    for (int t = 0; t < 4; ++t) {
      const float* row = &sD[w][t][lane][0];
      uint4 o;
      o.x = pk2(row[0], row[1]); o.y = pk2(row[2], row[3]);
      o.z = pk2(row[4], row[5]); o.w = pk2(row[6], row[7]);
      *(uint4*)(WTb + ((size_t)k * N + ibase + t * 16 + lane) * 8) = o;
    }
  }
}

// ---------------------------------------------------------------------------
// Output MLP via MFMA (r13 structure: one block per i, 12 k-groups/wave).
// Single change vs r13: XCD-chunked i mapping — consecutive i on the same
// XCD so the transposed gather WTb[krow][i] 64B lines (covering i..i+3) are
// fetched once per XCD instead of 4x across XCDs.
// ---------------------------------------------------------------------------
__global__ __launch_bounds__(256, 2) void out_mlp_mfma(
    const float* __restrict__ mtr, const short* __restrict__ WTb,
    const float* __restrict__ feat,
    const float* __restrict__ w0, const float* __restrict__ b0,
    const float* __restrict__ w1, const float* __restrict__ b1,
    const float* __restrict__ w2, const float* __restrict__ b2,
    const float* __restrict__ w3, const float* __restrict__ b3,
    float* __restrict__ out) {
  const int b = blockIdx.x;                    // 768 blocks
  const int i = (b & 7) * 96 + (b >> 3);       // XCD-chunked i
  const int w = threadIdx.x >> 6;
  const int col = threadIdx.x & 15;
  const int hi = (threadIdx.x >> 4) & 3;

  bf16x8 a0lo, a0hi, a1lo, a1hi, a2lo, a2hi, a3;
  {
    const float* p = w0 + col * 33;
    float4 xa = make_float4(p[hi * 4], p[hi * 4 + 1], p[hi * 4 + 2], p[hi * 4 + 3]);
    float4 xb = make_float4(p[16 + hi * 4], p[16 + hi * 4 + 1],
                            p[16 + hi * 4 + 2], p[16 + hi * 4 + 3]);
    a0lo = pack_frag(xa, xb);
    const float* q = w0 + (col + 16) * 33;
    float4 ya = make_float4(q[hi * 4], q[hi * 4 + 1], q[hi * 4 + 2], q[hi * 4 + 3]);
    float4 yb = make_float4(q[16 + hi * 4], q[16 + hi * 4 + 1],
                            q[16 + hi * 4 + 2], q[16 + hi * 4 + 3]);
    a0hi = pack_frag(ya, yb);
  }
  a1lo = pack_frag(*(const float4*)(w1 + col * 32 + hi * 4),
                   *(const float4*)(w1 + col * 32 + 16 + hi * 4));
  a1hi = pack_frag(*(const float4*)(w1 + (col + 16) * 32 + hi * 4),
                   *(const float4*)(w1 + (col + 16) * 32 + 16 + hi * 4));
  a2lo = pack_frag(*(const float4*)(w2 + col * 32 + hi * 4),
                   *(const float4*)(w2 + col * 32 + 16 + hi * 4));
  a2hi = pack_frag(*(const float4*)(w2 + (col + 16) * 32 + hi * 4),
                   *(const float4*)(w2 + (col + 16) * 32 + 16 + hi * 4));
  if (col < 8) {
    a3 = pack_frag(*(const float4*)(w3 + col * 32 + hi * 4),
                   *(const float4*)(w3 + col * 32 + 16 + hi * 4));
  } else {
    FragU z; z.u[0] = z.u[1] = z.u[2] = z.u[3] = 0; a3 = z.s;
  }

  const f32x4 c1a = ld4(b0 + hi * 4), c1b = ld4(b0 + 16 + hi * 4);
  const f32x4 c2a = ld4(b1 + hi * 4), c2b = ld4(b1 + 16 + hi * 4);
  const f32x4 c3a = ld4(b2 + hi * 4), c3b = ld4(b2 + 16 + hi * 4);
  f32x4 c4;
  if (hi < 2) c4 = ld4(b3 + hi * 4);
  else { c4[0] = c4[1] = c4[2] = c4[3] = 0.f; }

  float dg1[4], dg2[4];
#pragma unroll
  for (int r = 0; r < 4; ++r) {
    dg1[r] = w0[(hi * 4 + r) * 33 + 32];
    dg2[r] = w0[(16 + hi * 4 + r) * 33 + 32];
  }

#pragma unroll 1
  for (int g = 0; g < 12; ++g) {
    const int krow = w * 192 + g * 16 + col;

    FragU bf;
    const short* pW = (hi < 2)
        ? (WTb + ((size_t)krow * N + i) * 8 + (hi & 1) * 4)
        : (WTb + ((size_t)i * N + krow) * 8 + (hi & 1) * 4);
    uint2 wv2 = *(const uint2*)pW;
    const float* pF = (hi < 2) ? (feat + (size_t)krow * 8 + (hi & 1) * 4)
                               : (feat + (size_t)i * 8 + (hi & 1) * 4);
    float4 fv = *(const float4*)pF;
    bf.u[0] = wv2.x; bf.u[1] = wv2.y;
    bf.u[2] = pk2(fv.x, fv.y); bf.u[3] = pk2(fv.z, fv.w);
    bf16x8 bfr = bf.s;

    f32x4 d1 = c1a, d2 = c1b;
    d1 = __builtin_amdgcn_mfma_f32_16x16x32_bf16(a0lo, bfr, d1, 0, 0, 0);
    d2 = __builtin_amdgcn_mfma_f32_16x16x32_bf16(a0hi, bfr, d2, 0, 0, 0);
    const float eye = (krow == i) ? 1.f : 0.f;
#pragma unroll
    for (int r = 0; r < 4; ++r) {
      d1[r] = fmaf(eye, dg1[r], d1[r]);
      d2[r] = fmaf(eye, dg2[r], d2[r]);
    }
    bfr = relu_pack(d1, d2);

    d1 = c2a; d2 = c2b;
    d1 = __builtin_amdgcn_mfma_f32_16x16x32_bf16(a1lo, bfr, d1, 0, 0, 0);
    d2 = __builtin_amdgcn_mfma_f32_16x16x32_bf16(a1hi, bfr, d2, 0, 0, 0);
    bfr = relu_pack(d1, d2);

    d1 = c3a; d2 = c3b;
    d1 = __builtin_amdgcn_mfma_f32_16x16x32_bf16(a2lo, bfr, d1, 0, 0, 0);
    d2 = __builtin_amdgcn_mfma_f32_16x16x32_bf16(a2hi, bfr, d2, 0, 0, 0);
    bfr = relu_pack(d1, d2);

    f32x4 d3 = c4;
    d3 = __builtin_amdgcn_mfma_f32_16x16x32_bf16(a3, bfr, d3, 0, 0, 0);

    if (hi < 2) {
      const size_t idx = ((size_t)i * N + krow) * 8 + hi * 4;
      float4 m = *(const float4*)(mtr + idx);
      *(float4*)(out + idx) =
          make_float4(m.x + d3[0], m.y + d3[1], m.z + d3[2], m.w + d3[3]);
    }
  }
}

// ---------------------------------------------------------------------------
extern "C" void kernel_launch(void* const* d_in, const int* in_sizes, int n_in,
                              void* d_out, int out_size, void* d_ws,
                              size_t ws_size, hipStream_t stream) {
  const float* mtr  = (const float*)d_in[0];
  const float* feat = (const float*)d_in[1];
  const int*   ei   = (const int*)d_in[2];
  const float* ea   = (const float*)d_in[3];
  const float* ew0 = (const float*)d_in[4];
  const float* eb0 = (const float*)d_in[5];
  const float* ew1 = (const float*)d_in[6];
  const float* eb1 = (const float*)d_in[7];
  const float* ew2 = (const float*)d_in[8];
  const float* eb2 = (const float*)d_in[9];
  const float* ew3 = (const float*)d_in[10];
  const float* eb3 = (const float*)d_in[11];
  const float* ow0 = (const float*)d_in[12];
  const float* ob0 = (const float*)d_in[13];
  const float* ow1 = (const float*)d_in[14];
  const float* ob1 = (const float*)d_in[15];
  const float* ow2 = (const float*)d_in[16];
  const float* ob2 = (const float*)d_in[17];
  const float* ow3 = (const float*)d_in[18];
  const float* ob3 = (const float*)d_in[19];
  float* out = (float*)d_out;

  char* ws = (char*)d_ws;
  short* Mfrag = (short*)ws; ws += (size_t)NGROUPS * 512 * 2;     // 6.88 MB
  short* mtrT  = (short*)ws; ws += (size_t)N * N * 8 * 2;         // 9.44 MB
  short* WTb   = (short*)ws; ws += (size_t)N * N * 8 * 2;         // 9.44 MB
  int* winner  = (int*)ws;   ws += (size_t)N * N * 4;             // 2.36 MB
  int* deg     = (int*)ws;   ws += 1024 * 4;
  int* offs    = (int*)ws;   ws += 1024 * 4;
  int* curs    = (int*)ws;   ws += 1024 * 4;
  int* done_ctr = (int*)ws;  ws += 256 * 4;
  int* jlist   = (int*)ws;   ws += (size_t)NPAD_SLOTS * 4;        // 108 KB

  prep0<<<2304 + 1680, 256, 0, stream>>>(mtr, (uint4*)mtrT, (int4*)winner,
                                         (uint4*)Mfrag, jlist, deg, curs,
                                         done_ctr);
  edge_prep_scan<<<E / 256, 256, 0, stream>>>(ei, winner, deg, offs, done_ctr);
  edge_mlp_mfma<<<E / 64, 256, 0, stream>>>(feat, ei, ea, winner, offs, curs,
                                            jlist, ew0, eb0, ew1, eb1, ew2,
                                            eb2, ew3, eb3, Mfrag);
  contract7<<<2304, 256, 0, stream>>>(mtrT, Mfrag, jlist, offs, curs, WTb);
  out_mlp_mfma<<<N, 256, 0, stream>>>(mtr, WTb, feat, ow0, ob0, ow1, ob1, ow2,
                                      ob2, ow3, ob3, out);
}